// Round 11
// baseline (260.036 us; speedup 1.0000x reference)
//
#include <hip/hip_runtime.h>
#include <hip/hip_bf16.h>

#define B_ 64
#define T_ 2048
#define D_ 512     // K dim of GEMM
#define A_ 512     // attention dim (N of GEMM)
#define BMT 128    // t-rows per block
#define BNT 128    // a-cols per block (N split in 4)
#define NIT 4      // iterations; 2 K-tiles of 64 each

typedef float f32x4_t __attribute__((ext_vector_type(4)));
typedef short bf16x8_t __attribute__((ext_vector_type(8)));

#define GLL16(g, l) __builtin_amdgcn_global_load_lds( \
    (const __attribute__((address_space(1))) void*)(g), \
    (__attribute__((address_space(3))) void*)(l), 16, 0, 0)

#define SBAR __builtin_amdgcn_s_barrier()
#define LGKM0 do { asm volatile("s_waitcnt lgkmcnt(0)" ::: "memory"); \
                   __builtin_amdgcn_sched_barrier(0); } while (0)
#define VMW(N) asm volatile("s_waitcnt vmcnt(" #N ")" ::: "memory")

// ---------------- prep: q = query @ Wq + bq (fp32, exact), 4-way split ----------------
__global__ void __launch_bounds__(128) qproj_kernel(
    const float* __restrict__ query, const float* __restrict__ Wq,
    const float* __restrict__ bq, float* __restrict__ qbuf) {
  __shared__ float qs[D_];
  const int b = blockIdx.x, tid = threadIdx.x;
  const int col = blockIdx.y * 128 + tid;
  #pragma unroll
  for (int p = 0; p < 4; ++p) qs[p*128 + tid] = query[b*D_ + p*128 + tid];
  __syncthreads();
  float a0 = bq[col];
  #pragma unroll 8
  for (int d = 0; d < D_; ++d) a0 += qs[d] * Wq[d*A_ + col];
  qbuf[b*A_ + col] = a0;
}

// ---- prep: Wk [D][A] fp32 -> slab [kt=8][a=512][slot s = o ^ (a&7), 16B] ----
__global__ void __launch_bounds__(256) wkprep_kernel(
    const float* __restrict__ Wk, unsigned int* __restrict__ slab) {
  __shared__ float tile[64][65];
  const int kt = blockIdx.x >> 3;
  const int a0 = (blockIdx.x & 7) * 64;
  const int tid = threadIdx.x;
  #pragma unroll
  for (int p = 0; p < 16; ++p) {
    const int idx = p*256 + tid;
    const int k = idx >> 6, al = idx & 63;
    tile[k][al] = Wk[(kt*64 + k)*A_ + a0 + al];
  }
  __syncthreads();
  #pragma unroll
  for (int w = 0; w < 2; ++w) {
    const int idx = w*256 + tid;      // 0..511
    const int al = idx >> 3, c = idx & 7;
    const int a = a0 + al;
    const int s = c ^ (a & 7);
    union { __hip_bfloat162 h[2]; uint2 u; } x, y;
    x.h[0] = __float22bfloat162_rn(make_float2(tile[c*8+0][al], tile[c*8+1][al]));
    x.h[1] = __float22bfloat162_rn(make_float2(tile[c*8+2][al], tile[c*8+3][al]));
    y.h[0] = __float22bfloat162_rn(make_float2(tile[c*8+4][al], tile[c*8+5][al]));
    y.h[1] = __float22bfloat162_rn(make_float2(tile[c*8+6][al], tile[c*8+7][al]));
    *(uint4*)(slab + ((size_t)(kt*512 + a))*32 + s*4) =
        make_uint4(x.u.x, x.u.y, y.u.x, y.u.y);
  }
}

// ------- fused energy: 128x128 tile, 8-phase counted-vmcnt, 2 blocks/CU -------
// LDS: A0 @0 (16K), A1 @16384, B0 @32768 (16K), B1 @49152, red @65536 (1K)
__global__ void __launch_bounds__(256, 2) energy_kernel(
    const float* __restrict__ keys, const float* __restrict__ cover,
    const int* __restrict__ key_len, const unsigned char* __restrict__ slabB,
    const float* __restrict__ qbuf, const float* __restrict__ Wc,
    const float* __restrict__ Wo, float* __restrict__ epart) {
  __shared__ __align__(16) unsigned char lds[66560];

  const int d = blockIdx.x;                 // 0..4095; XCD swizzle, 4 ct of one panel co-XCD
  const int logical = (d & 7) * 512 + (d >> 3);
  const int ct = logical & 3;
  const int tt = (logical >> 2) & 15;
  const int b  = logical >> 6;
  const int t0 = tt * BMT;
  const int kl = key_len[b];
  if (t0 >= kl) return;

  const int tid = threadIdx.x;
  const int wid = tid >> 6, lane = tid & 63;
  const int lq = lane >> 4, lr = lane & 15;
  const int wm = wid >> 1, wn = wid & 1;    // 2x2 waves, 64x64 each
  const int sx = lr & 7;

  // fragment read bases (slot = octet ^ (row&7); row&7 == lr&7 for 16-multiples)
  const int aRow = (wm*64 + lr)*128;
  const int aOff0 = ((lq    ) ^ sx) << 4;   // kk=0
  const int aOff1 = ((4 + lq) ^ sx) << 4;   // kk=1
  const int bRow = (wn*64 + lr)*128;

  // A staging role: thread covers row sr (0..127), k-half sh (32 floats)
  const int sr = tid >> 1, sh = tid & 1;
  const float* akey = keys + ((size_t)b*T_ + t0 + sr)*(size_t)D_ + sh*32;
  unsigned char* const awr = lds + sr*128;
  const int srx = sr & 7;
  const int wof0 = ((sh*4+0) ^ srx) << 4;
  const int wof1 = ((sh*4+1) ^ srx) << 4;
  const int wof2 = ((sh*4+2) ^ srx) << 4;
  const int wof3 = ((sh*4+3) ^ srx) << 4;

  // B staging role: linear GLL copy of pre-swizzled slab rows (cols ct*128..+128)
  const unsigned char* bsl = slabB + (size_t)ct*16384 + tid*16;
  unsigned char* const bwr = lds + 32768 + tid*16;

  f32x4_t acc[4][4];
  #pragma unroll
  for (int i = 0; i < 4; ++i)
    #pragma unroll
    for (int j = 0; j < 4; ++j) acc[i][j] = 0.0f;

  bf16x8_t aF[4], bF[2];
  f32x4_t pA[8], qA[8];

#define AGLOAD(kt, ARR) { const float* p_ = akey + (kt)*64; \
    ARR[0] = *(const f32x4_t*)(p_);      ARR[1] = *(const f32x4_t*)(p_ + 4); \
    ARR[2] = *(const f32x4_t*)(p_ + 8);  ARR[3] = *(const f32x4_t*)(p_ + 12); \
    ARR[4] = *(const f32x4_t*)(p_ + 16); ARR[5] = *(const f32x4_t*)(p_ + 20); \
    ARR[6] = *(const f32x4_t*)(p_ + 24); ARR[7] = *(const f32x4_t*)(p_ + 28); }

#define PK16(dst, va, vb) { union { __hip_bfloat162 h[2]; uint2 u; } x_, y_; \
    x_.h[0] = __float22bfloat162_rn(make_float2(va[0], va[1])); \
    x_.h[1] = __float22bfloat162_rn(make_float2(va[2], va[3])); \
    y_.h[0] = __float22bfloat162_rn(make_float2(vb[0], vb[1])); \
    y_.h[1] = __float22bfloat162_rn(make_float2(vb[2], vb[3])); \
    *(uint4*)(dst) = make_uint4(x_.u.x, x_.u.y, y_.u.x, y_.u.y); }

#define APACK(buf, ARR) { \
    PK16(awr + (buf)*16384 + wof0, ARR[0], ARR[1]); \
    PK16(awr + (buf)*16384 + wof1, ARR[2], ARR[3]); \
    PK16(awr + (buf)*16384 + wof2, ARR[4], ARR[5]); \
    PK16(awr + (buf)*16384 + wof3, ARR[6], ARR[7]); }

#define BGLL4(kt, buf) { const unsigned char* g_ = bsl + (size_t)(kt)*65536; \
    unsigned char* l_ = bwr + (buf)*16384; \
    GLL16(g_, l_); GLL16(g_ + 4096, l_ + 4096); \
    GLL16(g_ + 8192, l_ + 8192); GLL16(g_ + 12288, l_ + 12288); }

#define DSRA(buf, kk) { const unsigned char* p_ = lds + (buf)*16384 + aRow + ((kk) ? aOff1 : aOff0); \
    aF[0] = *(const bf16x8_t*)(p_);        aF[1] = *(const bf16x8_t*)(p_ + 2048); \
    aF[2] = *(const bf16x8_t*)(p_ + 4096); aF[3] = *(const bf16x8_t*)(p_ + 6144); }

#define DSRB(buf, kk, nh) { const unsigned char* p_ = lds + 32768 + (buf)*16384 + bRow + ((kk) ? aOff1 : aOff0) + (nh)*4096; \
    bF[0] = *(const bf16x8_t*)(p_); bF[1] = *(const bf16x8_t*)(p_ + 2048); }

#define MFMA8(nh) { _Pragma("unroll") for (int mf_ = 0; mf_ < 4; ++mf_) { \
    _Pragma("unroll") for (int c_ = 0; c_ < 2; ++c_) \
      acc[mf_][(nh)*2 + c_] = __builtin_amdgcn_mfma_f32_16x16x32_bf16( \
          aF[mf_], bF[c_], acc[mf_][(nh)*2 + c_], 0, 0, 0); } }

#define PH_TAIL(nh) SBAR; LGKM0; __builtin_amdgcn_s_setprio(1); MFMA8(nh); \
    __builtin_amdgcn_s_setprio(0); SBAR

  // ---- prologue: stage K-tiles 0 (bufs 0) and 1 (bufs 1); one-time drain ----
  AGLOAD(0, pA); BGLL4(0, 0);
  AGLOAD(1, qA); BGLL4(1, 1);
  VMW(16); APACK(0, pA);
  VMW(4);  APACK(1, qA);
  VMW(0);
  LGKM0;
  SBAR;

  // ---- main loop: 4 iterations x 8 phases; c0=2it (buf0), c1=2it+1 (buf1) ----
  #pragma unroll
  for (int it = 0; it < NIT; ++it) {
    const int c1 = 2*it + 1, p0 = 2*it + 2, p1 = 2*it + 3;
    // ph1 (c0,kk0,nh0) + stage B(c1)->buf1
    DSRA(0, 0); DSRB(0, 0, 0);
    if (it >= 1) { BGLL4(c1, 1); }
    PH_TAIL(0);
    // ph2 (c0,kk0,nh1) + issue A-gloads(p0)
    DSRB(0, 0, 1);
    if (it <= 2) { AGLOAD(p0, pA); }
    PH_TAIL(1);
    // ph3 (c0,kk1,nh0) + pack A(c1)
    DSRA(0, 1); DSRB(0, 1, 0);
    if (it >= 1) {
      if (it <= 2) { VMW(12); } else { VMW(4); }
      APACK(1, qA);
    }
    PH_TAIL(0);
    // ph4 (c0,kk1,nh1) + B(c1) publication wait
    DSRB(0, 1, 1);
    if (it >= 1) { if (it <= 2) { VMW(8); } else { VMW(0); } }
    PH_TAIL(1);
    // ph5 (c1,kk0,nh0) + stage B(p0)->buf0
    DSRA(1, 0); DSRB(1, 0, 0);
    if (it <= 2) { BGLL4(p0, 0); }
    PH_TAIL(0);
    // ph6 (c1,kk0,nh1) + pack A(p0)
    DSRB(1, 0, 1);
    if (it <= 2) { VMW(4); APACK(0, pA); }
    PH_TAIL(1);
    // ph7 (c1,kk1,nh0)
    DSRA(1, 1); DSRB(1, 1, 0);
    PH_TAIL(0);
    // ph8 (c1,kk1,nh1) + issue A-gloads(p1) + B(p0) publication wait
    DSRB(1, 1, 1);
    if (it <= 2) { AGLOAD(p1, qA); VMW(8); }
    PH_TAIL(1);
  }

  // ---- epilogue: ep[t] = sum_n Wo[n] * tanh(acc + q[n] + cover[t]*Wc[n]) ----
  float* red = (float*)(lds + 65536);
  const float* qn  = qbuf + b*A_ + ct*BNT + wn*64 + lr;
  const float* wcn = Wc + ct*BNT + wn*64 + lr;
  const float* won = Wo + ct*BNT + wn*64 + lr;
  const float* covp = cover + (size_t)b*T_ + t0 + wm*64 + lq*4;
  float cov[4][4];
  #pragma unroll
  for (int mf = 0; mf < 4; ++mf)
    #pragma unroll
    for (int j = 0; j < 4; ++j) cov[mf][j] = covp[mf*16 + j];

  float ep[4][4];
  #pragma unroll
  for (int mf = 0; mf < 4; ++mf)
    #pragma unroll
    for (int j = 0; j < 4; ++j) ep[mf][j] = 0.f;

  #pragma unroll
  for (int nf = 0; nf < 4; ++nf) {
    const float qv = qn[nf*16];
    const float wc = wcn[nf*16];
    const float wo = won[nf*16];
    #pragma unroll
    for (int mf = 0; mf < 4; ++mf)
      #pragma unroll
      for (int j = 0; j < 4; ++j) {
        float p = acc[mf][nf][j] + qv + cov[mf][j] * wc;
        p = fminf(fmaxf(p, -15.f), 15.f);
        const float t2 = __expf(2.f * p);
        ep[mf][j] += wo * ((t2 - 1.f) * __builtin_amdgcn_rcpf(t2 + 1.f));
      }
  }
  #pragma unroll
  for (int mf = 0; mf < 4; ++mf)
    #pragma unroll
    for (int j = 0; j < 4; ++j) {
      float v = ep[mf][j];
      v += __shfl_xor(v, 1); v += __shfl_xor(v, 2);
      v += __shfl_xor(v, 4); v += __shfl_xor(v, 8);
      ep[mf][j] = v;
    }
  if (lr == 0) {
    #pragma unroll
    for (int mf = 0; mf < 4; ++mf)
      #pragma unroll
      for (int j = 0; j < 4; ++j)
        red[wid*64 + mf*16 + lq*4 + j] = ep[mf][j];
  }
  __syncthreads();
  if (tid < BMT) {
    const int r = tid, wmr = r >> 6, ro = r & 63;
    epart[((size_t)ct*B_ + b)*T_ + t0 + r] = red[wmr*128 + ro] + red[wmr*128 + 64 + ro];
  }
}

// ---------------- masked softmax over T (sums 4 col-partials) ----------------
__global__ void __launch_bounds__(1024) softmax_kernel(
    const float* __restrict__ epart, const int* __restrict__ key_len,
    float* __restrict__ attn) {
  __shared__ float sredM[16];
  __shared__ float sredS[16];
  const int b = blockIdx.x, tid = threadIdx.x;
  const int kl = key_len[b];
  float e0 = -3.0e38f, e1 = -3.0e38f;
  if (tid < kl)
    e0 = epart[(size_t)b*T_ + tid] + epart[((size_t)B_ + b)*T_ + tid]
       + epart[((size_t)2*B_ + b)*T_ + tid] + epart[((size_t)3*B_ + b)*T_ + tid];
  if (tid + 1024 < kl)
    e1 = epart[(size_t)b*T_ + tid+1024] + epart[((size_t)B_ + b)*T_ + tid+1024]
       + epart[((size_t)2*B_ + b)*T_ + tid+1024] + epart[((size_t)3*B_ + b)*T_ + tid+1024];
  float m = fmaxf(e0, e1);
  for (int s = 32; s; s >>= 1) m = fmaxf(m, __shfl_xor(m, s));
  if ((tid & 63) == 0) sredM[tid >> 6] = m;
  __syncthreads();
  float M = -3.0e38f;
  #pragma unroll
  for (int i = 0; i < 16; ++i) M = fmaxf(M, sredM[i]);
  const float p0 = (tid < kl) ? __expf(e0 - M) : 0.f;
  const float p1 = (tid + 1024 < kl) ? __expf(e1 - M) : 0.f;
  float s = p0 + p1;
  for (int k = 32; k; k >>= 1) s += __shfl_xor(s, k);
  if ((tid & 63) == 0) sredS[tid >> 6] = s;
  __syncthreads();
  float S = 0.f;
  #pragma unroll
  for (int i = 0; i < 16; ++i) S += sredS[i];
  const float inv = 1.f / S;
  attn[b*T_ + tid] = p0 * inv;
  attn[b*T_ + tid + 1024] = p1 * inv;
}

// ---------------- context: partial sums over 128-t chunks (float4), then combine ----------------
__global__ void __launch_bounds__(256) ctxpart_kernel(
    const float* __restrict__ value, const float* __restrict__ attn,
    const int* __restrict__ key_len, float* __restrict__ partial) {
  __shared__ float att_s[128];
  __shared__ float4 comb[128];
  const int b = blockIdx.y, ch = blockIdx.x;
  const int tid = threadIdx.x;
  const int c4 = tid & 127, half = tid >> 7;
  const int kl = key_len[b];
  const int tstart = ch * 128;
  const int tend = min(128, kl - tstart);
  float4 acc = make_float4(0.f, 0.f, 0.f, 0.f);
  if (tend > 0) {
    if (tid < 128) att_s[tid] = attn[b*T_ + tstart + tid];
    __syncthreads();
    const float4* vp = (const float4*)(value + ((size_t)b*T_ + tstart)*D_) + c4;
    for (int i = half; i < tend; i += 2) {
      const float w = att_s[i];
      const float4 v = vp[(size_t)i * 128];
      acc.x += w * v.x; acc.y += w * v.y; acc.z += w * v.z; acc.w += w * v.w;
    }
  }
  if (half == 1) comb[c4] = acc;
  __syncthreads();
  if (half == 0) {
    const float4 o = comb[c4];
    acc.x += o.x; acc.y += o.y; acc.z += o.z; acc.w += o.w;
    ((float4*)(partial + (size_t)(b*16 + ch)*D_))[c4] = acc;
  }
}

__global__ void __launch_bounds__(128) ctxsum_kernel(
    const float* __restrict__ partial, float* __restrict__ ctx) {
  const int b = blockIdx.x, tid = threadIdx.x;
  float4 s = make_float4(0.f, 0.f, 0.f, 0.f);
  #pragma unroll
  for (int c = 0; c < 16; ++c) {
    const float4 v = ((const float4*)(partial + (size_t)(b*16 + c)*D_))[tid];
    s.x += v.x; s.y += v.y; s.z += v.z; s.w += v.w;
  }
  ((float4*)(ctx + (size_t)b*D_))[tid] = s;
}

extern "C" void kernel_launch(void* const* d_in, const int* in_sizes, int n_in,
                              void* d_out, int out_size, void* d_ws, size_t ws_size,
                              hipStream_t stream) {
  const float* query  = (const float*)d_in[0];
  const float* keys   = (const float*)d_in[1];
  const float* value  = (const float*)d_in[2];
  const float* cover  = (const float*)d_in[3];
  const int*   key_len= (const int*)d_in[4];
  const float* Wq     = (const float*)d_in[5];
  const float* bq     = (const float*)d_in[6];
  const float* Wk     = (const float*)d_in[7];
  const float* Wc     = (const float*)d_in[8];
  const float* Wo     = (const float*)d_in[9];

  float* out = (float*)d_out;
  float* ctx_out  = out;            // [64,512]
  float* attn_out = out + B_*A_;    // [64,1,2048]

  float* ws = (float*)d_ws;
  float* qbuf    = ws;                                   // 32768 f32
  float* epart   = ws + 32768;                           // 4*131072 f32
  float* partial = ws + 32768 + 524288;                  // 524288 f32
  unsigned int* slab = (unsigned int*)(ws + 32768 + 524288 + 524288);  // 512 KB

  qproj_kernel<<<dim3(B_, 4), 128, 0, stream>>>(query, Wq, bq, qbuf);
  wkprep_kernel<<<64, 256, 0, stream>>>(Wk, slab);
  energy_kernel<<<B_*(T_/BMT)*(A_/BNT), 256, 0, stream>>>(
      keys, cover, key_len, (const unsigned char*)slab, qbuf, Wc, Wo, epart);
  softmax_kernel<<<B_, 1024, 0, stream>>>(epart, key_len, attn_out);
  ctxpart_kernel<<<dim3(16, B_), 256, 0, stream>>>(value, attn_out, key_len, partial);
  ctxsum_kernel<<<B_, 128, 0, stream>>>(partial, ctx_out);
}